// Round 2
// baseline (609.606 us; speedup 1.0000x reference)
//
#include <hip/hip_runtime.h>

#define B_ 512
#define F_ 128
#define D_ 1024
#define EPS_ 1e-5f

typedef float f32x4 __attribute__((ext_vector_type(4)));
typedef __bf16 bf16x8 __attribute__((ext_vector_type(8)));

// ---------------- LayerNorm over rows of D=1024, fp32 in -> fp32 out -------
__global__ __launch_bounds__(256) void k_ln_f32(
    const float* __restrict__ X, const float* __restrict__ g,
    const float* __restrict__ bv, float* __restrict__ Y) {
  int row = blockIdx.x, t = threadIdx.x;
  f32x4 xv = *(const f32x4*)(X + (size_t)row * D_ + t * 4);
  float s = xv[0] + xv[1] + xv[2] + xv[3];
  float ss = xv[0] * xv[0] + xv[1] * xv[1] + xv[2] * xv[2] + xv[3] * xv[3];
  __shared__ float r1[256], r2[256];
  r1[t] = s; r2[t] = ss;
  __syncthreads();
  for (int o = 128; o > 0; o >>= 1) {
    if (t < o) { r1[t] += r1[t + o]; r2[t] += r2[t + o]; }
    __syncthreads();
  }
  float mu = r1[0] * (1.0f / D_);
  float var = r2[0] * (1.0f / D_) - mu * mu;
  float rs = rsqrtf(var + EPS_);
  f32x4 gg = *(const f32x4*)(g + t * 4);
  f32x4 bb = *(const f32x4*)(bv + t * 4);
  f32x4 o4;
  o4[0] = (xv[0] - mu) * rs * gg[0] + bb[0];
  o4[1] = (xv[1] - mu) * rs * gg[1] + bb[1];
  o4[2] = (xv[2] - mu) * rs * gg[2] + bb[2];
  o4[3] = (xv[3] - mu) * rs * gg[3] + bb[3];
  *(f32x4*)(Y + (size_t)row * D_ + t * 4) = o4;
}

// ---------------- residual add + LayerNorm -> fp32 output ------------------
__global__ __launch_bounds__(256) void k_final(
    const float* __restrict__ X1, const float* __restrict__ X2,
    const float* __restrict__ g, const float* __restrict__ bv,
    float* __restrict__ out) {
  int row = blockIdx.x, t = threadIdx.x;
  f32x4 a = *(const f32x4*)(X1 + (size_t)row * D_ + t * 4);
  f32x4 b = *(const f32x4*)(X2 + (size_t)row * D_ + t * 4);
  float v0 = a[0] + b[0], v1 = a[1] + b[1], v2 = a[2] + b[2], v3 = a[3] + b[3];
  float s = v0 + v1 + v2 + v3;
  float ss = v0 * v0 + v1 * v1 + v2 * v2 + v3 * v3;
  __shared__ float r1[256], r2[256];
  r1[t] = s; r2[t] = ss;
  __syncthreads();
  for (int o = 128; o > 0; o >>= 1) {
    if (t < o) { r1[t] += r1[t + o]; r2[t] += r2[t + o]; }
    __syncthreads();
  }
  float mu = r1[0] * (1.0f / D_);
  float var = r2[0] * (1.0f / D_) - mu * mu;
  float rs = rsqrtf(var + EPS_);
  f32x4 gg = *(const f32x4*)(g + t * 4);
  f32x4 bb = *(const f32x4*)(bv + t * 4);
  f32x4 o4;
  o4[0] = (v0 - mu) * rs * gg[0] + bb[0];
  o4[1] = (v1 - mu) * rs * gg[1] + bb[1];
  o4[2] = (v2 - mu) * rs * gg[2] + bb[2];
  o4[3] = (v3 - mu) * rs * gg[3] + bb[3];
  *(f32x4*)(out + (size_t)row * D_ + t * 4) = o4;
}

// ---- GEMM: C[M,N] = A[M,K](f32) @ W[N,K](f32)^T + bias, split-bf16 MFMA ---
// One 16x16 tile per wave; verified fragment layout:
//   A/B frag: row = lane&15, k = (lane>>4)*8 + j ; C/D: col = lane&15, row = quad*4+reg
__global__ __launch_bounds__(64) void k_gemm_bt(
    const float* __restrict__ A, const float* __restrict__ W,
    const float* __restrict__ bias, float* __restrict__ C, int N, int K) {
  int lane = threadIdx.x;
  int r = lane & 15, quad = lane >> 4;
  int tn = blockIdx.x, tm = blockIdx.y;
  const float* arow = A + (size_t)(tm * 16 + r) * K + quad * 8;
  const float* wrow = W + (size_t)(tn * 16 + r) * K + quad * 8;
  f32x4 acc = {0.f, 0.f, 0.f, 0.f};
  for (int k0 = 0; k0 < K; k0 += 32) {
    f32x4 a0 = *(const f32x4*)(arow + k0);
    f32x4 a1 = *(const f32x4*)(arow + k0 + 4);
    f32x4 w0 = *(const f32x4*)(wrow + k0);
    f32x4 w1 = *(const f32x4*)(wrow + k0 + 4);
    bf16x8 ah, al, wh, wl;
#pragma unroll
    for (int i = 0; i < 4; i++) {
      float av = a0[i], wv = w0[i];
      ah[i] = (__bf16)av; al[i] = (__bf16)(av - (float)ah[i]);
      wh[i] = (__bf16)wv; wl[i] = (__bf16)(wv - (float)wh[i]);
    }
#pragma unroll
    for (int i = 0; i < 4; i++) {
      float av = a1[i], wv = w1[i];
      ah[i + 4] = (__bf16)av; al[i + 4] = (__bf16)(av - (float)ah[i + 4]);
      wh[i + 4] = (__bf16)wv; wl[i + 4] = (__bf16)(wv - (float)wh[i + 4]);
    }
    acc = __builtin_amdgcn_mfma_f32_16x16x32_bf16(ah, wh, acc, 0, 0, 0);
    acc = __builtin_amdgcn_mfma_f32_16x16x32_bf16(al, wh, acc, 0, 0, 0);
    acc = __builtin_amdgcn_mfma_f32_16x16x32_bf16(ah, wl, acc, 0, 0, 0);
  }
  int col = tn * 16 + r;
  float bb = bias ? bias[col] : 0.0f;
  int row0 = tm * 16 + quad * 4;
#pragma unroll
  for (int i = 0; i < 4; i++)
    C[(size_t)(row0 + i) * N + col] = acc[i] + bb;
}

// ---------------- transpose 1024x1024 fp32 (for q @ k_w) -------------------
__global__ __launch_bounds__(256) void k_transpose(
    const float* __restrict__ W, float* __restrict__ WT) {
  __shared__ float tile[32][33];
  int tj = blockIdx.x, ti = blockIdx.y;
  int c = threadIdx.x & 31, r0 = threadIdx.x >> 5;  // r0 in 0..7
#pragma unroll
  for (int i = 0; i < 4; i++) {
    int r = r0 + i * 8;
    tile[r][c] = W[(size_t)(ti * 32 + r) * D_ + tj * 32 + c];
  }
  __syncthreads();
#pragma unroll
  for (int i = 0; i < 4; i++) {
    int r = r0 + i * 8;
    WT[(size_t)(tj * 32 + r) * D_ + ti * 32 + c] = tile[c][r];
  }
}

// ---------------- per-b precompute from q2: gq, sum_gq, dot_bq, qkb --------
__global__ __launch_bounds__(256) void k_prep_q(
    const float* __restrict__ q2, const float* __restrict__ q,
    const float* __restrict__ g, const float* __restrict__ bv,
    const float* __restrict__ kb, float* __restrict__ gq,
    float* __restrict__ sum_gq, float* __restrict__ dot_bq, float* __restrict__ qkb) {
  int b = blockIdx.x, t = threadIdx.x;
  f32x4 q2v = *(const f32x4*)(q2 + (size_t)b * D_ + t * 4);
  f32x4 qv = *(const f32x4*)(q + (size_t)b * D_ + t * 4);
  f32x4 gg = *(const f32x4*)(g + t * 4);
  f32x4 bb = *(const f32x4*)(bv + t * 4);
  f32x4 kk = *(const f32x4*)(kb + t * 4);
  f32x4 gqv;
  gqv[0] = gg[0] * q2v[0]; gqv[1] = gg[1] * q2v[1];
  gqv[2] = gg[2] * q2v[2]; gqv[3] = gg[3] * q2v[3];
  *(f32x4*)(gq + (size_t)b * D_ + t * 4) = gqv;
  float s1 = gqv[0] + gqv[1] + gqv[2] + gqv[3];
  float s2 = bb[0] * q2v[0] + bb[1] * q2v[1] + bb[2] * q2v[2] + bb[3] * q2v[3];
  float s3 = kk[0] * qv[0] + kk[1] * qv[1] + kk[2] * qv[2] + kk[3] * qv[3];
  __shared__ float r1[256], r2[256], r3[256];
  r1[t] = s1; r2[t] = s2; r3[t] = s3;
  __syncthreads();
  for (int o = 128; o > 0; o >>= 1) {
    if (t < o) { r1[t] += r1[t + o]; r2[t] += r2[t + o]; r3[t] += r3[t + o]; }
    __syncthreads();
  }
  if (t == 0) { sum_gq[b] = r1[0]; dot_bq[b] = r2[0]; qkb[b] = r3[0]; }
}

// ---------------- video pass 1: LN stats + dot with gq -> logits -----------
// one wave per (b,f) row, 4 rows per block
__global__ __launch_bounds__(256) void k_vid_pass1(
    const float* __restrict__ video, const float* __restrict__ gq,
    const float* __restrict__ sum_gq, const float* __restrict__ dot_bq,
    const float* __restrict__ qkb, float* __restrict__ logits,
    float* __restrict__ meanv, float* __restrict__ rstdv) {
  int wave = threadIdx.x >> 6, lane = threadIdx.x & 63;
  int row = blockIdx.x * 4 + wave;  // row = b*F + f
  int b = row >> 7;
  const float* x = video + (size_t)row * D_;
  const float* gp = gq + (size_t)b * D_;
  float sx = 0.f, sxx = 0.f, sxg = 0.f;
#pragma unroll
  for (int c = 0; c < 4; c++) {
    int idx = c * 256 + lane * 4;
    f32x4 xx = *(const f32x4*)(x + idx);
    f32x4 gg = *(const f32x4*)(gp + idx);
    sx += xx[0] + xx[1] + xx[2] + xx[3];
    sxx += xx[0] * xx[0] + xx[1] * xx[1] + xx[2] * xx[2] + xx[3] * xx[3];
    sxg += xx[0] * gg[0] + xx[1] * gg[1] + xx[2] * gg[2] + xx[3] * gg[3];
  }
  for (int o = 32; o > 0; o >>= 1) {
    sx += __shfl_xor(sx, o);
    sxx += __shfl_xor(sxx, o);
    sxg += __shfl_xor(sxg, o);
  }
  if (lane == 0) {
    float mu = sx * (1.0f / D_);
    float var = sxx * (1.0f / D_) - mu * mu;
    float rs = rsqrtf(var + EPS_);
    float dot = rs * (sxg - mu * sum_gq[b]) + dot_bq[b] + qkb[b];
    logits[row] = dot * 0.03125f;  // 1/sqrt(1024)
    meanv[row] = mu;
    rstdv[row] = rs;
  }
}

// ---------------- softmax over F=128, produce a_f = w_f*rstd_f, c1 ---------
__global__ __launch_bounds__(64) void k_softmax(
    const float* __restrict__ logits, const float* __restrict__ meanv,
    const float* __restrict__ rstdv, float* __restrict__ aw, float* __restrict__ c1) {
  int b = blockIdx.x, t = threadIdx.x;
  int r = b * F_;
  float l0 = logits[r + t], l1 = logits[r + t + 64];
  float m = fmaxf(l0, l1);
  for (int o = 32; o > 0; o >>= 1) m = fmaxf(m, __shfl_xor(m, o));
  float e0 = expf(l0 - m), e1 = expf(l1 - m);
  float s = e0 + e1;
  for (int o = 32; o > 0; o >>= 1) s += __shfl_xor(s, o);
  float inv = 1.0f / s;
  float a0 = e0 * inv * rstdv[r + t];
  float a1 = e1 * inv * rstdv[r + t + 64];
  aw[r + t] = a0;
  aw[r + t + 64] = a1;
  float c = a0 * meanv[r + t] + a1 * meanv[r + t + 64];
  for (int o = 32; o > 0; o >>= 1) c += __shfl_xor(c, o);
  if (t == 0) c1[b] = c;
}

// ---------------- video pass 2: ctx[b,j] = g_j*(sum_f a_f x - c1) + b_j ----
__global__ __launch_bounds__(256) void k_vid_pass2(
    const float* __restrict__ video, const float* __restrict__ aw,
    const float* __restrict__ c1, const float* __restrict__ g,
    const float* __restrict__ bv, float* __restrict__ ctx) {
  int b = blockIdx.x, t = threadIdx.x;
  __shared__ float sa[F_];
  if (t < F_) sa[t] = aw[b * F_ + t];
  __syncthreads();
  const float* base = video + (size_t)b * F_ * D_ + t * 4;
  float s0 = 0.f, s1 = 0.f, s2 = 0.f, s3 = 0.f;
#pragma unroll 4
  for (int fi = 0; fi < F_; fi++) {
    f32x4 xx = *(const f32x4*)(base + (size_t)fi * D_);
    float af = sa[fi];
    s0 += af * xx[0];
    s1 += af * xx[1];
    s2 += af * xx[2];
    s3 += af * xx[3];
  }
  float cc = c1[b];
  f32x4 gg = *(const f32x4*)(g + t * 4);
  f32x4 bb = *(const f32x4*)(bv + t * 4);
  f32x4 o4;
  o4[0] = gg[0] * (s0 - cc) + bb[0];
  o4[1] = gg[1] * (s1 - cc) + bb[1];
  o4[2] = gg[2] * (s2 - cc) + bb[2];
  o4[3] = gg[3] * (s3 - cc) + bb[3];
  *(f32x4*)(ctx + (size_t)b * D_ + t * 4) = o4;
}

extern "C" void kernel_launch(void* const* d_in, const int* in_sizes, int n_in,
                              void* d_out, int out_size, void* d_ws, size_t ws_size,
                              hipStream_t stream) {
  (void)in_sizes; (void)n_in; (void)out_size; (void)ws_size;
  const float* text = (const float*)d_in[0];
  const float* video = (const float*)d_in[1];
  const float* q_w = (const float*)d_in[2];
  const float* k_w = (const float*)d_in[3];
  const float* v_w = (const float*)d_in[4];
  const float* out_w = (const float*)d_in[5];
  const float* lin_w = (const float*)d_in[6];
  const float* q_b = (const float*)d_in[7];
  const float* k_b = (const float*)d_in[8];
  const float* v_b = (const float*)d_in[9];
  const float* out_b = (const float*)d_in[10];
  const float* lin_b = (const float*)d_in[11];
  const float* ln1_g = (const float*)d_in[12];
  const float* ln1_b = (const float*)d_in[13];
  const float* ln2_g = (const float*)d_in[14];
  const float* ln2_b = (const float*)d_in[15];
  const float* ln3_g = (const float*)d_in[16];
  const float* ln3_b = (const float*)d_in[17];
  float* out = (float*)d_out;

  const size_t BD = (size_t)B_ * D_;  // 524288
  const size_t BF = (size_t)B_ * F_;  // 65536
  float* f = (float*)d_ws;
  float* slotA = f;             // BD
  float* slotB = f + BD;        // BD
  float* slotC = f + 2 * BD;    // BD
  float* k_wT = f + 3 * BD;     // D*D = 2*BD floats
  float* logits = f + 5 * BD;   // BF
  float* aw = logits + BF;
  float* meanv = logits + 2 * BF;
  float* rstdv = logits + 3 * BF;
  float* sum_gq = logits + 4 * BF;
  float* dot_bq = sum_gq + B_;
  float* qkb = sum_gq + 2 * B_;
  float* c1 = sum_gq + 3 * B_;
  // total ws use: 5*BD + 4*BF + 4*B_ floats ~ 11.5 MB

  dim3 gemm_grid(D_ / 16, B_ / 16);

  // q path: t_ln->A, qv->B, q2->A, gq->C
  k_ln_f32<<<B_, 256, 0, stream>>>(text, ln1_g, ln1_b, slotA);
  k_transpose<<<dim3(32, 32), 256, 0, stream>>>(k_w, k_wT);
  k_gemm_bt<<<gemm_grid, 64, 0, stream>>>(slotA, q_w, q_b, slotB, D_, D_);   // qv = t_ln@q_w^T
  k_gemm_bt<<<gemm_grid, 64, 0, stream>>>(slotB, k_wT, nullptr, slotA, D_, D_); // q2 = qv@k_w
  k_prep_q<<<B_, 256, 0, stream>>>(slotA, slotB, ln1_g, ln1_b, k_b, slotC,
                                   sum_gq, dot_bq, qkb);

  // attention over video without materializing K/V
  k_vid_pass1<<<BF / 4, 256, 0, stream>>>(video, slotC, sum_gq, dot_bq, qkb,
                                          logits, meanv, rstdv);
  k_softmax<<<B_, 64, 0, stream>>>(logits, meanv, rstdv, aw, c1);
  k_vid_pass2<<<B_, 256, 0, stream>>>(video, aw, c1, ln1_g, ln1_b, slotA); // ctx->A

  // output projections + norms: attn1->B, attn2->A, attno->C, lin->A
  k_gemm_bt<<<gemm_grid, 64, 0, stream>>>(slotA, v_w, v_b, slotB, D_, D_);   // attn1
  k_gemm_bt<<<gemm_grid, 64, 0, stream>>>(slotB, out_w, out_b, slotA, D_, D_); // attn2
  k_ln_f32<<<B_, 256, 0, stream>>>(slotA, ln2_g, ln2_b, slotC);              // attno
  k_gemm_bt<<<gemm_grid, 64, 0, stream>>>(slotC, lin_w, lin_b, slotA, D_, D_); // lin
  k_final<<<B_, 256, 0, stream>>>(slotC, slotA, ln3_g, ln3_b, out);
}

// Round 3
// 556.362 us; speedup vs baseline: 1.0957x; 1.0957x over previous
//
#include <hip/hip_runtime.h>

#define B_ 512
#define F_ 128
#define D_ 1024
#define EPS_ 1e-5f

typedef float f32x4 __attribute__((ext_vector_type(4)));
typedef __bf16 bf16x4 __attribute__((ext_vector_type(4)));
typedef __bf16 bf16x8 __attribute__((ext_vector_type(8)));

// ---------------- LayerNorm over rows of D=1024, fp32 in -> fp32 out -------
__global__ __launch_bounds__(256) void k_ln_f32(
    const float* __restrict__ X, const float* __restrict__ g,
    const float* __restrict__ bv, float* __restrict__ Y) {
  int row = blockIdx.x, t = threadIdx.x;
  f32x4 xv = *(const f32x4*)(X + (size_t)row * D_ + t * 4);
  float s = xv[0] + xv[1] + xv[2] + xv[3];
  float ss = xv[0] * xv[0] + xv[1] * xv[1] + xv[2] * xv[2] + xv[3] * xv[3];
  __shared__ float r1[256], r2[256];
  r1[t] = s; r2[t] = ss;
  __syncthreads();
  for (int o = 128; o > 0; o >>= 1) {
    if (t < o) { r1[t] += r1[t + o]; r2[t] += r2[t + o]; }
    __syncthreads();
  }
  float mu = r1[0] * (1.0f / D_);
  float var = r2[0] * (1.0f / D_) - mu * mu;
  float rs = rsqrtf(var + EPS_);
  f32x4 gg = *(const f32x4*)(g + t * 4);
  f32x4 bb = *(const f32x4*)(bv + t * 4);
  f32x4 o4;
  o4[0] = (xv[0] - mu) * rs * gg[0] + bb[0];
  o4[1] = (xv[1] - mu) * rs * gg[1] + bb[1];
  o4[2] = (xv[2] - mu) * rs * gg[2] + bb[2];
  o4[3] = (xv[3] - mu) * rs * gg[3] + bb[3];
  *(f32x4*)(Y + (size_t)row * D_ + t * 4) = o4;
}

// ---------------- residual add + LayerNorm -> fp32 output ------------------
__global__ __launch_bounds__(256) void k_final(
    const float* __restrict__ X1, const float* __restrict__ X2,
    const float* __restrict__ g, const float* __restrict__ bv,
    float* __restrict__ out) {
  int row = blockIdx.x, t = threadIdx.x;
  f32x4 a = *(const f32x4*)(X1 + (size_t)row * D_ + t * 4);
  f32x4 b = *(const f32x4*)(X2 + (size_t)row * D_ + t * 4);
  float v0 = a[0] + b[0], v1 = a[1] + b[1], v2 = a[2] + b[2], v3 = a[3] + b[3];
  float s = v0 + v1 + v2 + v3;
  float ss = v0 * v0 + v1 * v1 + v2 * v2 + v3 * v3;
  __shared__ float r1[256], r2[256];
  r1[t] = s; r2[t] = ss;
  __syncthreads();
  for (int o = 128; o > 0; o >>= 1) {
    if (t < o) { r1[t] += r1[t + o]; r2[t] += r2[t + o]; }
    __syncthreads();
  }
  float mu = r1[0] * (1.0f / D_);
  float var = r2[0] * (1.0f / D_) - mu * mu;
  float rs = rsqrtf(var + EPS_);
  f32x4 gg = *(const f32x4*)(g + t * 4);
  f32x4 bb = *(const f32x4*)(bv + t * 4);
  f32x4 o4;
  o4[0] = (v0 - mu) * rs * gg[0] + bb[0];
  o4[1] = (v1 - mu) * rs * gg[1] + bb[1];
  o4[2] = (v2 - mu) * rs * gg[2] + bb[2];
  o4[3] = (v3 - mu) * rs * gg[3] + bb[3];
  *(f32x4*)(out + (size_t)row * D_ + t * 4) = o4;
}

// ---------------- weight prep: fp32 -> bf16 (job 1 also transposes) --------
// grid (32, 32, 5), block 256
__global__ __launch_bounds__(256) void k_wprep(
    const float* __restrict__ w0, const float* __restrict__ w1,
    const float* __restrict__ w2, const float* __restrict__ w3,
    const float* __restrict__ w4, __bf16* __restrict__ o0,
    __bf16* __restrict__ o1, __bf16* __restrict__ o2,
    __bf16* __restrict__ o3, __bf16* __restrict__ o4p) {
  int z = blockIdx.z;
  const float* src = (z == 0) ? w0 : (z == 1) ? w1 : (z == 2) ? w2 : (z == 3) ? w3 : w4;
  __bf16* dst = (z == 0) ? o0 : (z == 1) ? o1 : (z == 2) ? o2 : (z == 3) ? o3 : o4p;
  int t = threadIdx.x;
  if (z != 1) {
    // straight convert: tile 32 rows x 32 cols
    int row = blockIdx.y * 32 + (t >> 3);
    int col = blockIdx.x * 32 + (t & 7) * 4;
    f32x4 v = *(const f32x4*)(src + (size_t)row * D_ + col);
    bf16x4 o;
    o[0] = (__bf16)v[0]; o[1] = (__bf16)v[1]; o[2] = (__bf16)v[2]; o[3] = (__bf16)v[3];
    *(bf16x4*)(dst + (size_t)row * D_ + col) = o;
  } else {
    // transpose + convert (k_w -> k_w^T)
    __shared__ float tile[32][33];
    int ti = blockIdx.y, tj = blockIdx.x;
    int c = t & 31, r0 = t >> 5;  // r0 in 0..7
#pragma unroll
    for (int i = 0; i < 4; i++) {
      int r = r0 + i * 8;
      tile[r][c] = src[(size_t)(ti * 32 + r) * D_ + tj * 32 + c];
    }
    __syncthreads();
#pragma unroll
    for (int i = 0; i < 4; i++) {
      int r = r0 + i * 8;
      dst[(size_t)(tj * 32 + r) * D_ + ti * 32 + c] = (__bf16)tile[c][r];
    }
  }
}

// ---- GEMM: C[M,N] = A[M,K](f32, hi/lo split) @ W[N,K](bf16)^T + bias ------
// 32x32 tile per wave (2x2 of 16x16 MFMA frags), register-prefetched K loop.
// Frag layout: A/B row = lane&15, k = (lane>>4)*8 + j ; C/D col = lane&15, row = quad*4+reg
__global__ __launch_bounds__(64) void k_gemm32(
    const float* __restrict__ A, const __bf16* __restrict__ W,
    const float* __restrict__ bias, float* __restrict__ C, int N, int K) {
  int lane = threadIdx.x;
  int r = lane & 15, quad = lane >> 4;
  int tn = blockIdx.x, tm = blockIdx.y;
  const float* pa0 = A + (size_t)(tm * 32 + r) * K + quad * 8;
  const float* pa1 = pa0 + (size_t)16 * K;
  const __bf16* pw0 = W + (size_t)(tn * 32 + r) * K + quad * 8;
  const __bf16* pw1 = pw0 + (size_t)16 * K;
  f32x4 acc00 = {0,0,0,0}, acc01 = {0,0,0,0}, acc10 = {0,0,0,0}, acc11 = {0,0,0,0};
  // prefetch k0 = 0
  f32x4 a0lo = *(const f32x4*)(pa0);
  f32x4 a0hi = *(const f32x4*)(pa0 + 4);
  f32x4 a1lo = *(const f32x4*)(pa1);
  f32x4 a1hi = *(const f32x4*)(pa1 + 4);
  bf16x8 w0v = *(const bf16x8*)(pw0);
  bf16x8 w1v = *(const bf16x8*)(pw1);
  for (int k0 = 0; k0 < K; k0 += 32) {
    int kn = (k0 + 32 < K) ? (k0 + 32) : 0;  // dummy-refetch on last iter
    f32x4 na0lo = *(const f32x4*)(pa0 + kn);
    f32x4 na0hi = *(const f32x4*)(pa0 + kn + 4);
    f32x4 na1lo = *(const f32x4*)(pa1 + kn);
    f32x4 na1hi = *(const f32x4*)(pa1 + kn + 4);
    bf16x8 nw0 = *(const bf16x8*)(pw0 + kn);
    bf16x8 nw1 = *(const bf16x8*)(pw1 + kn);
    // split A into hi/lo bf16
    bf16x8 ah0, al0, ah1, al1;
#pragma unroll
    for (int i = 0; i < 4; i++) {
      float v = a0lo[i];
      ah0[i] = (__bf16)v; al0[i] = (__bf16)(v - (float)ah0[i]);
      v = a0hi[i];
      ah0[i+4] = (__bf16)v; al0[i+4] = (__bf16)(v - (float)ah0[i+4]);
      v = a1lo[i];
      ah1[i] = (__bf16)v; al1[i] = (__bf16)(v - (float)ah1[i]);
      v = a1hi[i];
      ah1[i+4] = (__bf16)v; al1[i+4] = (__bf16)(v - (float)ah1[i+4]);
    }
    acc00 = __builtin_amdgcn_mfma_f32_16x16x32_bf16(ah0, w0v, acc00, 0, 0, 0);
    acc00 = __builtin_amdgcn_mfma_f32_16x16x32_bf16(al0, w0v, acc00, 0, 0, 0);
    acc01 = __builtin_amdgcn_mfma_f32_16x16x32_bf16(ah0, w1v, acc01, 0, 0, 0);
    acc01 = __builtin_amdgcn_mfma_f32_16x16x32_bf16(al0, w1v, acc01, 0, 0, 0);
    acc10 = __builtin_amdgcn_mfma_f32_16x16x32_bf16(ah1, w0v, acc10, 0, 0, 0);
    acc10 = __builtin_amdgcn_mfma_f32_16x16x32_bf16(al1, w0v, acc10, 0, 0, 0);
    acc11 = __builtin_amdgcn_mfma_f32_16x16x32_bf16(ah1, w1v, acc11, 0, 0, 0);
    acc11 = __builtin_amdgcn_mfma_f32_16x16x32_bf16(al1, w1v, acc11, 0, 0, 0);
    a0lo = na0lo; a0hi = na0hi; a1lo = na1lo; a1hi = na1hi;
    w0v = nw0; w1v = nw1;
  }
  int col0 = tn * 32 + r, col1 = col0 + 16;
  float b0 = bias ? bias[col0] : 0.0f;
  float b1 = bias ? bias[col1] : 0.0f;
  int row0 = tm * 32 + quad * 4;
#pragma unroll
  for (int i = 0; i < 4; i++) {
    C[(size_t)(row0 + i) * N + col0] = acc00[i] + b0;
    C[(size_t)(row0 + i) * N + col1] = acc01[i] + b1;
    C[(size_t)(row0 + 16 + i) * N + col0] = acc10[i] + b0;
    C[(size_t)(row0 + 16 + i) * N + col1] = acc11[i] + b1;
  }
}

// ---------------- per-b precompute from q2: gq, sum_gq, dot_bq, qkb --------
__global__ __launch_bounds__(256) void k_prep_q(
    const float* __restrict__ q2, const float* __restrict__ q,
    const float* __restrict__ g, const float* __restrict__ bv,
    const float* __restrict__ kb, float* __restrict__ gq,
    float* __restrict__ sum_gq, float* __restrict__ dot_bq, float* __restrict__ qkb) {
  int b = blockIdx.x, t = threadIdx.x;
  f32x4 q2v = *(const f32x4*)(q2 + (size_t)b * D_ + t * 4);
  f32x4 qv = *(const f32x4*)(q + (size_t)b * D_ + t * 4);
  f32x4 gg = *(const f32x4*)(g + t * 4);
  f32x4 bb = *(const f32x4*)(bv + t * 4);
  f32x4 kk = *(const f32x4*)(kb + t * 4);
  f32x4 gqv;
  gqv[0] = gg[0] * q2v[0]; gqv[1] = gg[1] * q2v[1];
  gqv[2] = gg[2] * q2v[2]; gqv[3] = gg[3] * q2v[3];
  *(f32x4*)(gq + (size_t)b * D_ + t * 4) = gqv;
  float s1 = gqv[0] + gqv[1] + gqv[2] + gqv[3];
  float s2 = bb[0] * q2v[0] + bb[1] * q2v[1] + bb[2] * q2v[2] + bb[3] * q2v[3];
  float s3 = kk[0] * qv[0] + kk[1] * qv[1] + kk[2] * qv[2] + kk[3] * qv[3];
  __shared__ float r1[256], r2[256], r3[256];
  r1[t] = s1; r2[t] = s2; r3[t] = s3;
  __syncthreads();
  for (int o = 128; o > 0; o >>= 1) {
    if (t < o) { r1[t] += r1[t + o]; r2[t] += r2[t + o]; r3[t] += r3[t + o]; }
    __syncthreads();
  }
  if (t == 0) { sum_gq[b] = r1[0]; dot_bq[b] = r2[0]; qkb[b] = r3[0]; }
}

// ---------------- fused flash-style attention over video -------------------
// one block (1024 threads) per b; video read from HBM exactly once.
// Online softmax over 4 tiles of 32 rows staged in LDS.
__global__ __launch_bounds__(1024) void k_attn(
    const float* __restrict__ video, const float* __restrict__ gq,
    const float* __restrict__ sum_gq, const float* __restrict__ dot_bq,
    const float* __restrict__ qkb, const float* __restrict__ g,
    const float* __restrict__ bv, float* __restrict__ ctx) {
  __shared__ float X[32][D_];            // 128 KB tile
  __shared__ float l_s[32], mu_s[32], rs_s[32], a_s[32];
  __shared__ float alpha_s, S_s, C_s;
  int b = blockIdx.x, t = threadIdx.x;
  int row = t >> 5, c = t & 31;          // phase-A mapping: 32 threads per row
  const float* vbase = video + ((size_t)b * F_ + row) * D_ + c * 32;
  // per-thread gq slice (cols c*32 .. c*32+31), loaded once
  f32x4 gqr[8];
  const float* gp = gq + (size_t)b * D_ + c * 32;
#pragma unroll
  for (int i = 0; i < 8; i++) gqr[i] = *(const f32x4*)(gp + i * 4);
  float sgq = sum_gq[b], dbq = dot_bq[b], qk = qkb[b];
  // preload tile 0
  f32x4 vr[8];
#pragma unroll
  for (int i = 0; i < 8; i++) vr[i] = *(const f32x4*)(vbase + i * 4);
  float O = 0.0f;           // column accumulator (phase-C mapping: col = t)
  float m_run = -1e30f, S = 0.0f, Cc = 0.0f;  // softmax state (live in wave 0)
  for (int T = 0; T < 4; T++) {
    // phase A: stats + stage to LDS
    float sx = 0.f, sxx = 0.f, sxg = 0.f;
#pragma unroll
    for (int i = 0; i < 8; i++) {
      f32x4 v = vr[i];
      sx += v[0] + v[1] + v[2] + v[3];
      sxx += v[0]*v[0] + v[1]*v[1] + v[2]*v[2] + v[3]*v[3];
      f32x4 gg = gqr[i];
      sxg += v[0]*gg[0] + v[1]*gg[1] + v[2]*gg[2] + v[3]*gg[3];
      *(f32x4*)(&X[row][c * 32 + i * 4]) = v;
    }
#pragma unroll
    for (int o = 16; o > 0; o >>= 1) {
      sx += __shfl_xor(sx, o);
      sxx += __shfl_xor(sxx, o);
      sxg += __shfl_xor(sxg, o);
    }
    if (c == 0) {
      float mu = sx * (1.0f / D_);
      float var = sxx * (1.0f / D_) - mu * mu;
      float rs = rsqrtf(var + EPS_);
      l_s[row] = (rs * (sxg - mu * sgq) + dbq + qk) * 0.03125f;
      mu_s[row] = mu; rs_s[row] = rs;
    }
    // issue next-tile loads now; latency overlaps barriers + phases B/C
    if (T < 3) {
      const float* nb = vbase + (size_t)(T + 1) * 32 * D_;
#pragma unroll
      for (int i = 0; i < 8; i++) vr[i] = *(const f32x4*)(nb + i * 4);
    }
    __syncthreads();
    // phase B: online-softmax update (lanes 0..31 of wave 0)
    if (t < 32) {
      float lf = l_s[t], mt = lf;
#pragma unroll
      for (int o = 16; o > 0; o >>= 1) mt = fmaxf(mt, __shfl_xor(mt, o));
      float m_new = fmaxf(m_run, mt);
      float alpha = __expf(m_run - m_new);
      float e = __expf(lf - m_new);
      float af = e * rs_s[t];
      a_s[t] = af;
      float se = e, sc = af * mu_s[t];
#pragma unroll
      for (int o = 16; o > 0; o >>= 1) {
        se += __shfl_xor(se, o);
        sc += __shfl_xor(sc, o);
      }
      S = S * alpha + se;
      Cc = Cc * alpha + sc;
      m_run = m_new;
      if (t == 0) { alpha_s = alpha; S_s = S; C_s = Cc; }
    }
    __syncthreads();
    // phase C: column accumulation from LDS
    float alpha = alpha_s;
    float acc = 0.0f;
#pragma unroll
    for (int fi = 0; fi < 32; fi++) acc += a_s[fi] * X[fi][t];
    O = O * alpha + acc;
    if (T < 3) __syncthreads();  // protect X/a_s before next tile overwrites
  }
  float inv = 1.0f / S_s;
  ctx[(size_t)b * D_ + t] = g[t] * ((O - C_s) * inv) + bv[t];
}

extern "C" void kernel_launch(void* const* d_in, const int* in_sizes, int n_in,
                              void* d_out, int out_size, void* d_ws, size_t ws_size,
                              hipStream_t stream) {
  (void)in_sizes; (void)n_in; (void)out_size; (void)ws_size;
  const float* text = (const float*)d_in[0];
  const float* video = (const float*)d_in[1];
  const float* q_w = (const float*)d_in[2];
  const float* k_w = (const float*)d_in[3];
  const float* v_w = (const float*)d_in[4];
  const float* out_w = (const float*)d_in[5];
  const float* lin_w = (const float*)d_in[6];
  const float* q_b = (const float*)d_in[7];
  const float* k_b = (const float*)d_in[8];
  const float* v_b = (const float*)d_in[9];
  const float* out_b = (const float*)d_in[10];
  const float* lin_b = (const float*)d_in[11];
  const float* ln1_g = (const float*)d_in[12];
  const float* ln1_b = (const float*)d_in[13];
  const float* ln2_g = (const float*)d_in[14];
  const float* ln2_b = (const float*)d_in[15];
  const float* ln3_g = (const float*)d_in[16];
  const float* ln3_b = (const float*)d_in[17];
  float* out = (float*)d_out;

  const size_t BD = (size_t)B_ * D_;   // 524288
  const size_t DD = (size_t)D_ * D_;   // 1048576
  float* f = (float*)d_ws;
  float* slotA = f;            // BD
  float* slotB = f + BD;       // BD
  float* slotC = f + 2 * BD;   // BD
  float* sum_gq = f + 3 * BD;
  float* dot_bq = sum_gq + B_;
  float* qkb = sum_gq + 2 * B_;
  __bf16* Wq = (__bf16*)(sum_gq + 4 * B_);
  __bf16* WkT = Wq + DD;
  __bf16* Wv = Wq + 2 * DD;
  __bf16* Wo = Wq + 3 * DD;
  __bf16* Wl = Wq + 4 * DD;
  // total ws use: ~16.3 MB

  dim3 gemm_grid(D_ / 32, B_ / 32);  // (32, 16)

  // weight prep (independent of everything else)
  k_wprep<<<dim3(32, 32, 5), 256, 0, stream>>>(q_w, k_w, v_w, out_w, lin_w,
                                               Wq, WkT, Wv, Wo, Wl);
  // q path: t_ln->A, qv->B, q2->A, gq->C
  k_ln_f32<<<B_, 256, 0, stream>>>(text, ln1_g, ln1_b, slotA);
  k_gemm32<<<gemm_grid, 64, 0, stream>>>(slotA, Wq, q_b, slotB, D_, D_);     // qv
  k_gemm32<<<gemm_grid, 64, 0, stream>>>(slotB, WkT, nullptr, slotA, D_, D_); // q2
  k_prep_q<<<B_, 256, 0, stream>>>(slotA, slotB, ln1_g, ln1_b, k_b, slotC,
                                   sum_gq, dot_bq, qkb);
  // fused attention: video read once; ctx->A
  k_attn<<<B_, 1024, 0, stream>>>(video, slotC, sum_gq, dot_bq, qkb,
                                  ln1_g, ln1_b, slotA);
  // output projections + norms
  k_gemm32<<<gemm_grid, 64, 0, stream>>>(slotA, Wv, v_b, slotB, D_, D_);     // attn1
  k_gemm32<<<gemm_grid, 64, 0, stream>>>(slotB, Wo, out_b, slotA, D_, D_);   // attn2
  k_ln_f32<<<B_, 256, 0, stream>>>(slotA, ln2_g, ln2_b, slotC);              // attno
  k_gemm32<<<gemm_grid, 64, 0, stream>>>(slotC, Wl, lin_b, slotA, D_, D_);   // lin
  k_final<<<B_, 256, 0, stream>>>(slotC, slotA, ln3_g, ln3_b, out);
}

// Round 4
// 523.415 us; speedup vs baseline: 1.1647x; 1.0629x over previous
//
#include <hip/hip_runtime.h>

#define B_ 512
#define F_ 128
#define D_ 1024
#define EPS_ 1e-5f

typedef float f32x4 __attribute__((ext_vector_type(4)));
typedef __bf16 bf16x4 __attribute__((ext_vector_type(4)));
typedef __bf16 bf16x8 __attribute__((ext_vector_type(8)));

// ---- LayerNorm rows of D=1024, fp32 in; OUT=0: fp32 out, OUT=1: bf16 hi/lo
template <int OUT>
__global__ __launch_bounds__(256) void k_ln(
    const float* __restrict__ X, const float* __restrict__ g,
    const float* __restrict__ bv, float* __restrict__ Yf,
    __bf16* __restrict__ Yh, __bf16* __restrict__ Yl) {
  int row = blockIdx.x, t = threadIdx.x;
  f32x4 xv = *(const f32x4*)(X + (size_t)row * D_ + t * 4);
  float s = xv[0] + xv[1] + xv[2] + xv[3];
  float ss = xv[0] * xv[0] + xv[1] * xv[1] + xv[2] * xv[2] + xv[3] * xv[3];
#pragma unroll
  for (int o = 32; o > 0; o >>= 1) { s += __shfl_xor(s, o); ss += __shfl_xor(ss, o); }
  __shared__ float ws[4][2];
  int w = t >> 6;
  if ((t & 63) == 0) { ws[w][0] = s; ws[w][1] = ss; }
  __syncthreads();
  s = ws[0][0] + ws[1][0] + ws[2][0] + ws[3][0];
  ss = ws[0][1] + ws[1][1] + ws[2][1] + ws[3][1];
  float mu = s * (1.0f / D_);
  float var = ss * (1.0f / D_) - mu * mu;
  float rs = rsqrtf(var + EPS_);
  f32x4 gg = *(const f32x4*)(g + t * 4);
  f32x4 bb = *(const f32x4*)(bv + t * 4);
  f32x4 o4;
#pragma unroll
  for (int i = 0; i < 4; i++) o4[i] = (xv[i] - mu) * rs * gg[i] + bb[i];
  if (OUT == 0) {
    *(f32x4*)(Yf + (size_t)row * D_ + t * 4) = o4;
  } else {
    bf16x4 h4, l4;
#pragma unroll
    for (int i = 0; i < 4; i++) {
      h4[i] = (__bf16)o4[i];
      l4[i] = (__bf16)(o4[i] - (float)h4[i]);
    }
    *(bf16x4*)(Yh + (size_t)row * D_ + t * 4) = h4;
    *(bf16x4*)(Yl + (size_t)row * D_ + t * 4) = l4;
  }
}

// ---- residual add + LayerNorm -> fp32 output (X1 = hi/lo planes, X2 fp32) -
__global__ __launch_bounds__(256) void k_final(
    const __bf16* __restrict__ X1h, const __bf16* __restrict__ X1l,
    const float* __restrict__ X2, const float* __restrict__ g,
    const float* __restrict__ bv, float* __restrict__ out) {
  int row = blockIdx.x, t = threadIdx.x;
  bf16x4 h4 = *(const bf16x4*)(X1h + (size_t)row * D_ + t * 4);
  bf16x4 l4 = *(const bf16x4*)(X1l + (size_t)row * D_ + t * 4);
  f32x4 b = *(const f32x4*)(X2 + (size_t)row * D_ + t * 4);
  f32x4 v;
#pragma unroll
  for (int i = 0; i < 4; i++) v[i] = (float)h4[i] + (float)l4[i] + b[i];
  float s = v[0] + v[1] + v[2] + v[3];
  float ss = v[0] * v[0] + v[1] * v[1] + v[2] * v[2] + v[3] * v[3];
#pragma unroll
  for (int o = 32; o > 0; o >>= 1) { s += __shfl_xor(s, o); ss += __shfl_xor(ss, o); }
  __shared__ float ws[4][2];
  int w = t >> 6;
  if ((t & 63) == 0) { ws[w][0] = s; ws[w][1] = ss; }
  __syncthreads();
  s = ws[0][0] + ws[1][0] + ws[2][0] + ws[3][0];
  ss = ws[0][1] + ws[1][1] + ws[2][1] + ws[3][1];
  float mu = s * (1.0f / D_);
  float var = ss * (1.0f / D_) - mu * mu;
  float rs = rsqrtf(var + EPS_);
  f32x4 gg = *(const f32x4*)(g + t * 4);
  f32x4 bb = *(const f32x4*)(bv + t * 4);
  f32x4 o4;
#pragma unroll
  for (int i = 0; i < 4; i++) o4[i] = (v[i] - mu) * rs * gg[i] + bb[i];
  *(f32x4*)(out + (size_t)row * D_ + t * 4) = o4;
}

// ---------------- weight prep: fp32 -> bf16 (job 1 also transposes) --------
__global__ __launch_bounds__(256) void k_wprep(
    const float* __restrict__ w0, const float* __restrict__ w1,
    const float* __restrict__ w2, const float* __restrict__ w3,
    const float* __restrict__ w4, __bf16* __restrict__ o0,
    __bf16* __restrict__ o1, __bf16* __restrict__ o2,
    __bf16* __restrict__ o3, __bf16* __restrict__ o4p) {
  int z = blockIdx.z;
  const float* src = (z == 0) ? w0 : (z == 1) ? w1 : (z == 2) ? w2 : (z == 3) ? w3 : w4;
  __bf16* dst = (z == 0) ? o0 : (z == 1) ? o1 : (z == 2) ? o2 : (z == 3) ? o3 : o4p;
  int t = threadIdx.x;
  if (z != 1) {
    int row = blockIdx.y * 32 + (t >> 3);
    int col = blockIdx.x * 32 + (t & 7) * 4;
    f32x4 v = *(const f32x4*)(src + (size_t)row * D_ + col);
    bf16x4 o;
    o[0] = (__bf16)v[0]; o[1] = (__bf16)v[1]; o[2] = (__bf16)v[2]; o[3] = (__bf16)v[3];
    *(bf16x4*)(dst + (size_t)row * D_ + col) = o;
  } else {
    __shared__ float tile[32][33];
    int ti = blockIdx.y, tj = blockIdx.x;
    int c = t & 31, r0 = t >> 5;
#pragma unroll
    for (int i = 0; i < 4; i++) {
      int r = r0 + i * 8;
      tile[r][c] = src[(size_t)(ti * 32 + r) * D_ + tj * 32 + c];
    }
    __syncthreads();
#pragma unroll
    for (int i = 0; i < 4; i++) {
      int r = r0 + i * 8;
      dst[(size_t)(tj * 32 + r) * D_ + ti * 32 + c] = (__bf16)tile[c][r];
    }
  }
}

// ---- GEMM: C[M,N] = (Ah+Al)[M,K] @ W[N,K]^T + bias. 32x32 tile per wave. --
// OUT=0: fp32 C; OUT=1: bf16 hi/lo planes. Zero per-iter VALU: pure load+MFMA.
// Frag layout: A/B row = lane&15, k = (lane>>4)*8+j ; C/D col = lane&15, row = quad*4+reg
template <int OUT>
__global__ __launch_bounds__(64) void k_gemm32(
    const __bf16* __restrict__ Ah, const __bf16* __restrict__ Al,
    const __bf16* __restrict__ W, const float* __restrict__ bias,
    float* __restrict__ Cf, __bf16* __restrict__ Ch, __bf16* __restrict__ Cl,
    int N, int K) {
  int lane = threadIdx.x;
  int r = lane & 15, quad = lane >> 4;
  int tn = blockIdx.x, tm = blockIdx.y;
  const __bf16* pah0 = Ah + (size_t)(tm * 32 + r) * K + quad * 8;
  const __bf16* pah1 = pah0 + (size_t)16 * K;
  const __bf16* pal0 = Al + (size_t)(tm * 32 + r) * K + quad * 8;
  const __bf16* pal1 = pal0 + (size_t)16 * K;
  const __bf16* pw0 = W + (size_t)(tn * 32 + r) * K + quad * 8;
  const __bf16* pw1 = pw0 + (size_t)16 * K;
  f32x4 acc00 = {0,0,0,0}, acc01 = {0,0,0,0}, acc10 = {0,0,0,0}, acc11 = {0,0,0,0};
  bf16x8 ah0 = *(const bf16x8*)pah0, ah1 = *(const bf16x8*)pah1;
  bf16x8 al0 = *(const bf16x8*)pal0, al1 = *(const bf16x8*)pal1;
  bf16x8 w0v = *(const bf16x8*)pw0, w1v = *(const bf16x8*)pw1;
  for (int k0 = 0; k0 < K; k0 += 32) {
    int kn = (k0 + 32 < K) ? (k0 + 32) : 0;  // dummy refetch on last iter
    bf16x8 nah0 = *(const bf16x8*)(pah0 + kn);
    bf16x8 nah1 = *(const bf16x8*)(pah1 + kn);
    bf16x8 nal0 = *(const bf16x8*)(pal0 + kn);
    bf16x8 nal1 = *(const bf16x8*)(pal1 + kn);
    bf16x8 nw0 = *(const bf16x8*)(pw0 + kn);
    bf16x8 nw1 = *(const bf16x8*)(pw1 + kn);
    acc00 = __builtin_amdgcn_mfma_f32_16x16x32_bf16(ah0, w0v, acc00, 0, 0, 0);
    acc01 = __builtin_amdgcn_mfma_f32_16x16x32_bf16(ah0, w1v, acc01, 0, 0, 0);
    acc10 = __builtin_amdgcn_mfma_f32_16x16x32_bf16(ah1, w0v, acc10, 0, 0, 0);
    acc11 = __builtin_amdgcn_mfma_f32_16x16x32_bf16(ah1, w1v, acc11, 0, 0, 0);
    acc00 = __builtin_amdgcn_mfma_f32_16x16x32_bf16(al0, w0v, acc00, 0, 0, 0);
    acc01 = __builtin_amdgcn_mfma_f32_16x16x32_bf16(al0, w1v, acc01, 0, 0, 0);
    acc10 = __builtin_amdgcn_mfma_f32_16x16x32_bf16(al1, w0v, acc10, 0, 0, 0);
    acc11 = __builtin_amdgcn_mfma_f32_16x16x32_bf16(al1, w1v, acc11, 0, 0, 0);
    ah0 = nah0; ah1 = nah1; al0 = nal0; al1 = nal1; w0v = nw0; w1v = nw1;
  }
  int col0 = tn * 32 + r, col1 = col0 + 16;
  float b0 = bias ? bias[col0] : 0.0f;
  float b1 = bias ? bias[col1] : 0.0f;
  int row0 = tm * 32 + quad * 4;
#pragma unroll
  for (int i = 0; i < 4; i++) {
    float v00 = acc00[i] + b0, v01 = acc01[i] + b1;
    float v10 = acc10[i] + b0, v11 = acc11[i] + b1;
    size_t o00 = (size_t)(row0 + i) * N + col0, o01 = (size_t)(row0 + i) * N + col1;
    size_t o10 = (size_t)(row0 + 16 + i) * N + col0, o11 = (size_t)(row0 + 16 + i) * N + col1;
    if (OUT == 0) {
      Cf[o00] = v00; Cf[o01] = v01; Cf[o10] = v10; Cf[o11] = v11;
    } else {
      __bf16 h;
      h = (__bf16)v00; Ch[o00] = h; Cl[o00] = (__bf16)(v00 - (float)h);
      h = (__bf16)v01; Ch[o01] = h; Cl[o01] = (__bf16)(v01 - (float)h);
      h = (__bf16)v10; Ch[o10] = h; Cl[o10] = (__bf16)(v10 - (float)h);
      h = (__bf16)v11; Ch[o11] = h; Cl[o11] = (__bf16)(v11 - (float)h);
    }
  }
}

// ---------------- per-b precompute from q2: gq, sum_gq, dot_bq, qkb --------
__global__ __launch_bounds__(256) void k_prep_q(
    const float* __restrict__ q2, const __bf16* __restrict__ qh,
    const __bf16* __restrict__ ql, const float* __restrict__ g,
    const float* __restrict__ bv, const float* __restrict__ kb,
    float* __restrict__ gq, float* __restrict__ sum_gq,
    float* __restrict__ dot_bq, float* __restrict__ qkb) {
  int b = blockIdx.x, t = threadIdx.x;
  f32x4 q2v = *(const f32x4*)(q2 + (size_t)b * D_ + t * 4);
  bf16x4 h4 = *(const bf16x4*)(qh + (size_t)b * D_ + t * 4);
  bf16x4 l4 = *(const bf16x4*)(ql + (size_t)b * D_ + t * 4);
  f32x4 gg = *(const f32x4*)(g + t * 4);
  f32x4 bb = *(const f32x4*)(bv + t * 4);
  f32x4 kk = *(const f32x4*)(kb + t * 4);
  f32x4 gqv;
  float s1 = 0.f, s2 = 0.f, s3 = 0.f;
#pragma unroll
  for (int i = 0; i < 4; i++) {
    gqv[i] = gg[i] * q2v[i];
    s1 += gqv[i];
    s2 += bb[i] * q2v[i];
    s3 += kk[i] * ((float)h4[i] + (float)l4[i]);
  }
  *(f32x4*)(gq + (size_t)b * D_ + t * 4) = gqv;
#pragma unroll
  for (int o = 32; o > 0; o >>= 1) {
    s1 += __shfl_xor(s1, o); s2 += __shfl_xor(s2, o); s3 += __shfl_xor(s3, o);
  }
  __shared__ float ws[4][3];
  int w = t >> 6;
  if ((t & 63) == 0) { ws[w][0] = s1; ws[w][1] = s2; ws[w][2] = s3; }
  __syncthreads();
  if (t == 0) {
    sum_gq[b] = ws[0][0] + ws[1][0] + ws[2][0] + ws[3][0];
    dot_bq[b] = ws[0][1] + ws[1][1] + ws[2][1] + ws[3][1];
    qkb[b] = ws[0][2] + ws[1][2] + ws[2][2] + ws[3][2];
  }
}

// ---------------- fused flash-style attention over video -------------------
// one block (1024 threads) per b; video read from HBM exactly once.
// Interleaved col mapping (4c+128i) + row pad 8 -> LDS writes at b128 floor.
#define XPAD 1032
__global__ __launch_bounds__(1024) void k_attn(
    const float* __restrict__ video, const float* __restrict__ gq,
    const float* __restrict__ sum_gq, const float* __restrict__ dot_bq,
    const float* __restrict__ qkb, const float* __restrict__ g,
    const float* __restrict__ bv, __bf16* __restrict__ ctxh,
    __bf16* __restrict__ ctxl) {
  __shared__ float X[32][XPAD];          // 132 KB -> 1 block/CU
  __shared__ float l_s[32], mu_s[32], rs_s[32], a_s[32];
  __shared__ float alpha_s, S_s, C_s;
  int b = blockIdx.x, t = threadIdx.x;
  int row = t >> 5, c = t & 31;          // phase-A mapping
  const float* vbase = video + ((size_t)b * F_ + row) * D_ + c * 4;
  f32x4 gqr[8];
  const float* gp = gq + (size_t)b * D_ + c * 4;
#pragma unroll
  for (int i = 0; i < 8; i++) gqr[i] = *(const f32x4*)(gp + i * 128);
  float sgq = sum_gq[b], dbq = dot_bq[b], qk = qkb[b];
  f32x4 vr[8];
#pragma unroll
  for (int i = 0; i < 8; i++) vr[i] = *(const f32x4*)(vbase + i * 128);
  float O = 0.0f;
  float m_run = -1e30f, S = 0.0f, Cc = 0.0f;
  for (int T = 0; T < 4; T++) {
    float sx = 0.f, sxx = 0.f, sxg = 0.f;
#pragma unroll
    for (int i = 0; i < 8; i++) {
      f32x4 v = vr[i];
      sx += v[0] + v[1] + v[2] + v[3];
      sxx += v[0]*v[0] + v[1]*v[1] + v[2]*v[2] + v[3]*v[3];
      f32x4 gg = gqr[i];
      sxg += v[0]*gg[0] + v[1]*gg[1] + v[2]*gg[2] + v[3]*gg[3];
      *(f32x4*)(&X[row][c * 4 + i * 128]) = v;
    }
#pragma unroll
    for (int o = 16; o > 0; o >>= 1) {
      sx += __shfl_xor(sx, o);
      sxx += __shfl_xor(sxx, o);
      sxg += __shfl_xor(sxg, o);
    }
    if (c == 0) {
      float mu = sx * (1.0f / D_);
      float var = sxx * (1.0f / D_) - mu * mu;
      float rs = rsqrtf(var + EPS_);
      l_s[row] = (rs * (sxg - mu * sgq) + dbq + qk) * 0.03125f;
      mu_s[row] = mu; rs_s[row] = rs;
    }
    if (T < 3) {
      const float* nb = vbase + (size_t)(T + 1) * 32 * D_;
#pragma unroll
      for (int i = 0; i < 8; i++) vr[i] = *(const f32x4*)(nb + i * 128);
    }
    __syncthreads();
    if (t < 32) {
      float lf = l_s[t], mt = lf;
#pragma unroll
      for (int o = 16; o > 0; o >>= 1) mt = fmaxf(mt, __shfl_xor(mt, o));
      float m_new = fmaxf(m_run, mt);
      float alpha = __expf(m_run - m_new);
      float e = __expf(lf - m_new);
      float af = e * rs_s[t];
      a_s[t] = af;
      float se = e, sc = af * mu_s[t];
#pragma unroll
      for (int o = 16; o > 0; o >>= 1) {
        se += __shfl_xor(se, o);
        sc += __shfl_xor(sc, o);
      }
      S = S * alpha + se;
      Cc = Cc * alpha + sc;
      m_run = m_new;
      if (t == 0) { alpha_s = alpha; S_s = S; C_s = Cc; }
    }
    __syncthreads();
    float alpha = alpha_s;
    float acc = 0.0f;
#pragma unroll
    for (int fi = 0; fi < 32; fi++) acc += a_s[fi] * X[fi][t];
    O = O * alpha + acc;
    if (T < 3) __syncthreads();
  }
  float inv = 1.0f / S_s;
  float v = g[t] * ((O - C_s) * inv) + bv[t];
  __bf16 h = (__bf16)v;
  ctxh[(size_t)b * D_ + t] = h;
  ctxl[(size_t)b * D_ + t] = (__bf16)(v - (float)h);
}

extern "C" void kernel_launch(void* const* d_in, const int* in_sizes, int n_in,
                              void* d_out, int out_size, void* d_ws, size_t ws_size,
                              hipStream_t stream) {
  (void)in_sizes; (void)n_in; (void)out_size; (void)ws_size;
  const float* text = (const float*)d_in[0];
  const float* video = (const float*)d_in[1];
  const float* q_w = (const float*)d_in[2];
  const float* k_w = (const float*)d_in[3];
  const float* v_w = (const float*)d_in[4];
  const float* out_w = (const float*)d_in[5];
  const float* lin_w = (const float*)d_in[6];
  const float* q_b = (const float*)d_in[7];
  const float* k_b = (const float*)d_in[8];
  const float* v_b = (const float*)d_in[9];
  const float* out_b = (const float*)d_in[10];
  const float* lin_b = (const float*)d_in[11];
  const float* ln1_g = (const float*)d_in[12];
  const float* ln1_b = (const float*)d_in[13];
  const float* ln2_g = (const float*)d_in[14];
  const float* ln2_b = (const float*)d_in[15];
  const float* ln3_g = (const float*)d_in[16];
  const float* ln3_b = (const float*)d_in[17];
  float* out = (float*)d_out;

  const size_t BD = (size_t)B_ * D_;   // 524288
  const size_t DD = (size_t)D_ * D_;   // 1048576
  float* f = (float*)d_ws;
  float* slotF1 = f;            // BD fp32 (q2, attn2)
  float* slotF2 = f + BD;       // BD fp32 (gq, lin)
  float* sum_gq = f + 2 * BD;
  float* dot_bq = sum_gq + B_;
  float* qkb = sum_gq + 2 * B_;
  __bf16* P1h = (__bf16*)(sum_gq + 4 * B_);   // plane pair 1 (t_ln, ctx)
  __bf16* P1l = P1h + BD;
  __bf16* P2h = P1h + 2 * BD;                 // plane pair 2 (qv, attn1)
  __bf16* P2l = P1h + 3 * BD;
  __bf16* P3h = P1h + 4 * BD;                 // plane pair 3 (attno)
  __bf16* P3l = P1h + 5 * BD;
  __bf16* Wq = P1h + 6 * BD;
  __bf16* WkT = Wq + DD;
  __bf16* Wv = Wq + 2 * DD;
  __bf16* Wo = Wq + 3 * DD;
  __bf16* Wl = Wq + 4 * DD;
  // total ws use: ~24.5 MB

  dim3 gemm_grid(D_ / 32, B_ / 32);  // (32, 16)

  k_wprep<<<dim3(32, 32, 5), 256, 0, stream>>>(q_w, k_w, v_w, out_w, lin_w,
                                               Wq, WkT, Wv, Wo, Wl);
  // q path
  k_ln<1><<<B_, 256, 0, stream>>>(text, ln1_g, ln1_b, nullptr, P1h, P1l);      // t_ln
  k_gemm32<1><<<gemm_grid, 64, 0, stream>>>(P1h, P1l, Wq, q_b, nullptr, P2h, P2l, D_, D_);   // qv
  k_gemm32<0><<<gemm_grid, 64, 0, stream>>>(P2h, P2l, WkT, nullptr, slotF1, nullptr, nullptr, D_, D_); // q2
  k_prep_q<<<B_, 256, 0, stream>>>(slotF1, P2h, P2l, ln1_g, ln1_b, k_b,
                                   slotF2, sum_gq, dot_bq, qkb);               // gq -> slotF2
  // fused attention: video read once; ctx -> P1 planes
  k_attn<<<B_, 1024, 0, stream>>>(video, slotF2, sum_gq, dot_bq, qkb,
                                  ln1_g, ln1_b, P1h, P1l);
  // output projections + norms
  k_gemm32<1><<<gemm_grid, 64, 0, stream>>>(P1h, P1l, Wv, v_b, nullptr, P2h, P2l, D_, D_);   // attn1
  k_gemm32<0><<<gemm_grid, 64, 0, stream>>>(P2h, P2l, Wo, out_b, slotF1, nullptr, nullptr, D_, D_); // attn2
  k_ln<1><<<B_, 256, 0, stream>>>(slotF1, ln2_g, ln2_b, nullptr, P3h, P3l);    // attno
  k_gemm32<0><<<gemm_grid, 64, 0, stream>>>(P3h, P3l, Wl, lin_b, slotF2, nullptr, nullptr, D_, D_); // lin
  k_final<<<B_, 256, 0, stream>>>(P3h, P3l, slotF2, ln3_g, ln3_b, out);
}